// Round 2
// baseline (537.849 us; speedup 1.0000x reference)
//
#include <hip/hip_runtime.h>

// LinearConv2D: y[b, o=g*8+n, fi, t] =
//   sum_{d<8, fr<2, w<16} x[b, g*8+d, 2*fi+fr, 4*t+w] * wt[g*8+n, d, 2*fi+fr, w]
// Shapes: x[16,64,128,256] f32, wt[64,8,128,16] f32, out[16,64,64,61] f32.
//
// R2: latency/occupancy fix.
//  - 256-thread blocks = 4 waves, each wave owns one fi -> 2048 blocks,
//    8 blocks/CU = 32 waves/CU (R1's 64-thread blocks hit the CU workgroup
//    slot limit at ~13 waves -> Occupancy 42%).
//  - __launch_bounds__(256, 8) (VGPR cap 64; R1 compiled to 20 VGPRs and
//    serialized its loads) + d-loop unroll x4 so ~8 float4 loads are in
//    flight per wave.
// Weight addresses are wave-uniform -> scalar (s_load) pipe, as in R1
// (SGPR=112 confirmed).

namespace {
constexpr int kB  = 16;
constexpr int kC  = 64;
constexpr int kF  = 128;
constexpr int kT  = 256;
constexpr int kG  = 8;
constexpr int kD  = 8;
constexpr int kN  = 8;
constexpr int kW  = 16;
constexpr int kKS = 4;
constexpr int kNT = 61;   // (256-16)/4 + 1
constexpr int kO  = 64;
constexpr int kFP = 64;   // (128-2)/2 + 1
}

__global__ __launch_bounds__(256, 8)
void lc2d_kernel(const float* __restrict__ x,
                 const float* __restrict__ wt,
                 float* __restrict__ out) {
  const int lane = threadIdx.x & 63;   // t
  const int wv   = threadIdx.x >> 6;   // which fi within the block
  const int fi   = blockIdx.x * 4 + wv;  // 0..63
  const int g    = blockIdx.y;           // 0..7
  const int b    = blockIdx.z;           // 0..15

  // Clamp inactive lanes so their (dead) loads stay in-bounds.
  const int tc   = (lane < kNT - 1) ? lane : (kNT - 1);
  const int tau0 = tc * kKS;    // max 240; +15 = 255 in bounds

  // x[b, g*8+d, 2*fi+fr, tau]
  const float* xbase = x + (((size_t)b * kC + g * kD) * kF + fi * 2) * kT;
  // wt[(g*8+n)*kD*kF*kW + ...] with f = 2*fi+fr
  const float* wbase = wt + ((size_t)(g * kN) * kD * kF + fi * 2) * (size_t)kW;

  float acc[kN];
#pragma unroll
  for (int n = 0; n < kN; ++n) acc[n] = 0.f;

#pragma unroll 4
  for (int d = 0; d < kD; ++d) {
#pragma unroll
    for (int fr = 0; fr < 2; ++fr) {
      const float* xr = xbase + ((size_t)d * kF + fr) * kT + tau0;
      const float4 v0 = *(const float4*)(xr + 0);
      const float4 v1 = *(const float4*)(xr + 4);
      const float4 v2 = *(const float4*)(xr + 8);
      const float4 v3 = *(const float4*)(xr + 12);
      const float xv[16] = {v0.x, v0.y, v0.z, v0.w,
                            v1.x, v1.y, v1.z, v1.w,
                            v2.x, v2.y, v2.z, v2.w,
                            v3.x, v3.y, v3.z, v3.w};
#pragma unroll
      for (int n = 0; n < kN; ++n) {
        // Uniform address (blockIdx + loop indices only) -> s_load
        const float* wr = wbase + (((size_t)n * kD + d) * kF + fr) * (size_t)kW;
#pragma unroll
        for (int wq = 0; wq < 4; ++wq) {
          const float4 wvv = *(const float4*)(wr + 4 * wq);
          acc[n] = fmaf(xv[4 * wq + 0], wvv.x, acc[n]);
          acc[n] = fmaf(xv[4 * wq + 1], wvv.y, acc[n]);
          acc[n] = fmaf(xv[4 * wq + 2], wvv.z, acc[n]);
          acc[n] = fmaf(xv[4 * wq + 3], wvv.w, acc[n]);
        }
      }
    }
  }

  if (lane < kNT) {
    float* ob = out + (((size_t)b * kO + g * kN) * kFP + fi) * (size_t)kNT + lane;
#pragma unroll
    for (int n = 0; n < kN; ++n) {
      ob[(size_t)n * kFP * kNT] = acc[n];
    }
  }
}

extern "C" void kernel_launch(void* const* d_in, const int* in_sizes, int n_in,
                              void* d_out, int out_size, void* d_ws, size_t ws_size,
                              hipStream_t stream) {
  const float* x  = (const float*)d_in[0];
  const float* wt = (const float*)d_in[1];
  float* out      = (float*)d_out;

  dim3 grid(kFP / 4, kG, kB);   // 16 x 8 x 16 = 2048 blocks of 256 threads
  lc2d_kernel<<<grid, 256, 0, stream>>>(x, wt, out);
}

// Round 3
// 348.576 us; speedup vs baseline: 1.5430x; 1.5430x over previous
//
#include <hip/hip_runtime.h>

// LinearConv2D: y[b, o=g*8+n, fi, t] =
//   sum_{d<8, fr<2, w<16} x[b, g*8+d, 2*fi+fr, 4*t+w] * wt[g*8+n, d, 2*fi+fr, w]
// Shapes: x[16,64,128,256] f32, wt[64,8,128,16] f32, out[16,64,64,61] f32.
//
// R3: R2's 404us regression was scratch spill (FETCH 358MB / WRITE 543MB
// steady-state): the xv[16] local array + unroll4 got demoted to scratch at
// the 64-VGPR cap. Fix:
//  - keep 256-thread blocks (occupancy 78% validated in R2)
//  - __launch_bounds__(256,4) -> 128 VGPR cap
//  - NO local arrays; explicit float4 register double-buffer: prefetch next
//    (d,fr) row's 4 float4s, then 128 FMAs on current row (256 cy of FMA
//    issue hides the L1-hit load latency; 8 waves/SIMD TLP on top).
// VALU floor: 16 rows x 128 fmac x 2cy = 4096 cy/wave, 8 waves/SIMD -> ~14us.

namespace {
constexpr int kB  = 16;
constexpr int kC  = 64;
constexpr int kF  = 128;
constexpr int kT  = 256;
constexpr int kG  = 8;
constexpr int kD  = 8;
constexpr int kN  = 8;
constexpr int kW  = 16;
constexpr int kKS = 4;
constexpr int kNT = 61;   // (256-16)/4 + 1
constexpr int kO  = 64;
constexpr int kFP = 64;   // (128-2)/2 + 1
constexpr int kWStride = kD * kF * kW;  // per-n weight stride (floats)
}

__device__ __forceinline__ void fma_row(const float4& x0, const float4& x1,
                                        const float4& x2, const float4& x3,
                                        const float* __restrict__ wr,
                                        float& acc) {
  const float4 w0 = ((const float4*)wr)[0];
  const float4 w1 = ((const float4*)wr)[1];
  const float4 w2 = ((const float4*)wr)[2];
  const float4 w3 = ((const float4*)wr)[3];
  acc = fmaf(x0.x, w0.x, acc);
  acc = fmaf(x0.y, w0.y, acc);
  acc = fmaf(x0.z, w0.z, acc);
  acc = fmaf(x0.w, w0.w, acc);
  acc = fmaf(x1.x, w1.x, acc);
  acc = fmaf(x1.y, w1.y, acc);
  acc = fmaf(x1.z, w1.z, acc);
  acc = fmaf(x1.w, w1.w, acc);
  acc = fmaf(x2.x, w2.x, acc);
  acc = fmaf(x2.y, w2.y, acc);
  acc = fmaf(x2.z, w2.z, acc);
  acc = fmaf(x2.w, w2.w, acc);
  acc = fmaf(x3.x, w3.x, acc);
  acc = fmaf(x3.y, w3.y, acc);
  acc = fmaf(x3.z, w3.z, acc);
  acc = fmaf(x3.w, w3.w, acc);
}

__global__ __launch_bounds__(256, 4)
void lc2d_kernel(const float* __restrict__ x,
                 const float* __restrict__ wt,
                 float* __restrict__ out) {
  const int lane = threadIdx.x & 63;     // t
  const int wv   = threadIdx.x >> 6;     // fi within block
  const int fi   = blockIdx.x * 4 + wv;  // 0..63
  const int g    = blockIdx.y;           // 0..7
  const int b    = blockIdx.z;           // 0..15

  // Clamp inactive lanes so their (dead) loads stay in-bounds.
  const int tc   = (lane < kNT - 1) ? lane : (kNT - 1);
  const int tau0 = tc * kKS;             // max 240; +15 = 255 in bounds

  // x[b, g*8+d, 2*fi+fr, tau]; row(it=d*2+fr) offset = d*kF*kT + fr*kT
  const float* xbase = x + (((size_t)b * kC + g * kD) * kF + fi * 2) * kT + tau0;
  // wt[(g*8+n), d, 2*fi+fr, w]
  const float* wbase = wt + ((size_t)(g * kN) * kD * kF + fi * 2) * (size_t)kW;

  float a0 = 0.f, a1 = 0.f, a2 = 0.f, a3 = 0.f;
  float a4 = 0.f, a5 = 0.f, a6 = 0.f, a7 = 0.f;

  // Prime the register double-buffer with row 0 (d=0, fr=0).
  float4 c0 = ((const float4*)xbase)[0];
  float4 c1 = ((const float4*)xbase)[1];
  float4 c2 = ((const float4*)xbase)[2];
  float4 c3 = ((const float4*)xbase)[3];

#pragma unroll 2
  for (int it = 0; it < 16; ++it) {
    // Prefetch next row (clamped; it==15 reloads row 15 — harmless L1 hit).
    const int nx = (it < 15) ? it + 1 : 15;
    const float* xrn = xbase + ((size_t)(nx >> 1) * kF + (nx & 1)) * kT;
    float4 p0 = ((const float4*)xrn)[0];
    float4 p1 = ((const float4*)xrn)[1];
    float4 p2 = ((const float4*)xrn)[2];
    float4 p3 = ((const float4*)xrn)[3];

    // Weight row for (d=it>>1, fr=it&1); wave-uniform address -> scalar pipe.
    const float* wr = wbase + (((size_t)(it >> 1) * kF + (it & 1))) * kW;
    fma_row(c0, c1, c2, c3, wr + 0 * kWStride, a0);
    fma_row(c0, c1, c2, c3, wr + 1 * kWStride, a1);
    fma_row(c0, c1, c2, c3, wr + 2 * kWStride, a2);
    fma_row(c0, c1, c2, c3, wr + 3 * kWStride, a3);
    fma_row(c0, c1, c2, c3, wr + 4 * kWStride, a4);
    fma_row(c0, c1, c2, c3, wr + 5 * kWStride, a5);
    fma_row(c0, c1, c2, c3, wr + 6 * kWStride, a6);
    fma_row(c0, c1, c2, c3, wr + 7 * kWStride, a7);

    c0 = p0; c1 = p1; c2 = p2; c3 = p3;
  }

  if (lane < kNT) {
    float* ob = out + (((size_t)b * kO + g * kN) * kFP + fi) * (size_t)kNT + lane;
    const size_t s = (size_t)kFP * kNT;
    ob[0 * s] = a0;
    ob[1 * s] = a1;
    ob[2 * s] = a2;
    ob[3 * s] = a3;
    ob[4 * s] = a4;
    ob[5 * s] = a5;
    ob[6 * s] = a6;
    ob[7 * s] = a7;
  }
}

extern "C" void kernel_launch(void* const* d_in, const int* in_sizes, int n_in,
                              void* d_out, int out_size, void* d_ws, size_t ws_size,
                              hipStream_t stream) {
  const float* x  = (const float*)d_in[0];
  const float* wt = (const float*)d_in[1];
  float* out      = (float*)d_out;

  dim3 grid(kFP / 4, kG, kB);   // 16 x 8 x 16 = 2048 blocks of 256 threads
  lc2d_kernel<<<grid, 256, 0, stream>>>(x, wt, out);
}

// Round 4
// 211.060 us; speedup vs baseline: 2.5483x; 1.6515x over previous
//
#include <hip/hip_runtime.h>

// LinearConv2D: y[b, o=g*8+n, fi, t] =
//   sum_{d<8, fr<2, w<16} x[b, g*8+d, 2*fi+fr, 4*t+w] * wt[g*8+n, d, 2*fi+fr, w]
// Shapes: x[16,64,128,256] f32, wt[64,8,128,16] f32, out[16,64,64,61] f32.
//
// R4: R3's 212us was caused by fi = blockIdx.x*4 + (threadIdx.x>>6): the
// compiler can't prove threadIdx.x>>6 wave-uniform, so weight loads became
// per-lane VECTOR loads (SGPR 112->64 between R1 and R3 is the evidence),
// serializing on VMEM latency. Weights depend only on (g,fi) — so keep
// (fi,g) purely in blockIdx (provably scalar -> s_load) and let the 4 waves
// of a block take 4 different b values (b only affects x/out, which are
// per-lane vector accesses anyway).
//  - 2048 blocks x 256 threads -> 8 blocks/CU = 32 waves/CU.
//  - x register double-buffer, no local arrays (R3: validated, no spill).
//  - weights in SGPRs -> ~45 VGPRs -> __launch_bounds__(256,8).

namespace {
constexpr int kB  = 16;
constexpr int kC  = 64;
constexpr int kF  = 128;
constexpr int kT  = 256;
constexpr int kG  = 8;
constexpr int kD  = 8;
constexpr int kN  = 8;
constexpr int kW  = 16;
constexpr int kKS = 4;
constexpr int kNT = 61;   // (256-16)/4 + 1
constexpr int kO  = 64;
constexpr int kFP = 64;   // (128-2)/2 + 1
constexpr int kWStride = kD * kF * kW;  // per-n weight stride (floats)
}

__device__ __forceinline__ void fma_row(const float4& x0, const float4& x1,
                                        const float4& x2, const float4& x3,
                                        const float* __restrict__ wr,
                                        float& acc) {
  const float4 w0 = ((const float4*)wr)[0];
  const float4 w1 = ((const float4*)wr)[1];
  const float4 w2 = ((const float4*)wr)[2];
  const float4 w3 = ((const float4*)wr)[3];
  acc = fmaf(x0.x, w0.x, acc);
  acc = fmaf(x0.y, w0.y, acc);
  acc = fmaf(x0.z, w0.z, acc);
  acc = fmaf(x0.w, w0.w, acc);
  acc = fmaf(x1.x, w1.x, acc);
  acc = fmaf(x1.y, w1.y, acc);
  acc = fmaf(x1.z, w1.z, acc);
  acc = fmaf(x1.w, w1.w, acc);
  acc = fmaf(x2.x, w2.x, acc);
  acc = fmaf(x2.y, w2.y, acc);
  acc = fmaf(x2.z, w2.z, acc);
  acc = fmaf(x2.w, w2.w, acc);
  acc = fmaf(x3.x, w3.x, acc);
  acc = fmaf(x3.y, w3.y, acc);
  acc = fmaf(x3.z, w3.z, acc);
  acc = fmaf(x3.w, w3.w, acc);
}

__global__ __launch_bounds__(256, 8)
void lc2d_kernel(const float* __restrict__ x,
                 const float* __restrict__ wt,
                 float* __restrict__ out) {
  const int lane = threadIdx.x & 63;            // t
  const int wv   = threadIdx.x >> 6;            // b within block (per-lane OK)
  const int fi   = blockIdx.x;                  // 0..63  (scalar!)
  const int g    = blockIdx.y;                  // 0..7   (scalar!)
  const int b    = blockIdx.z * 4 + wv;         // 0..15

  // Clamp inactive lanes so their (dead) loads stay in-bounds.
  const int tc   = (lane < kNT - 1) ? lane : (kNT - 1);
  const int tau0 = tc * kKS;                    // max 240; +15 = 255 in bounds

  // x[b, g*8+d, 2*fi+fr, tau]; row(it=d*2+fr) offset = d*kF*kT + fr*kT
  const float* xbase = x + (((size_t)b * kC + g * kD) * kF + fi * 2) * kT + tau0;
  // wt[(g*8+n), d, 2*fi+fr, w] — depends ONLY on blockIdx -> s_load.
  const float* wbase = wt + ((size_t)(g * kN) * kD * kF + fi * 2) * (size_t)kW;

  float a0 = 0.f, a1 = 0.f, a2 = 0.f, a3 = 0.f;
  float a4 = 0.f, a5 = 0.f, a6 = 0.f, a7 = 0.f;

  // Prime the x register double-buffer with row 0 (d=0, fr=0).
  float4 c0 = ((const float4*)xbase)[0];
  float4 c1 = ((const float4*)xbase)[1];
  float4 c2 = ((const float4*)xbase)[2];
  float4 c3 = ((const float4*)xbase)[3];

#pragma unroll 2
  for (int it = 0; it < 16; ++it) {
    // Prefetch next x row (it==15 reloads row 15 — harmless L1 hit).
    const int nx = (it < 15) ? it + 1 : 15;
    const float* xrn = xbase + ((size_t)(nx >> 1) * kF + (nx & 1)) * kT;
    float4 p0 = ((const float4*)xrn)[0];
    float4 p1 = ((const float4*)xrn)[1];
    float4 p2 = ((const float4*)xrn)[2];
    float4 p3 = ((const float4*)xrn)[3];

    // Weight row for (d=it>>1, fr=it&1); scalar address -> s_load_dwordx16.
    const float* wr = wbase + (((size_t)(it >> 1) * kF + (it & 1))) * kW;
    fma_row(c0, c1, c2, c3, wr + 0 * kWStride, a0);
    fma_row(c0, c1, c2, c3, wr + 1 * kWStride, a1);
    fma_row(c0, c1, c2, c3, wr + 2 * kWStride, a2);
    fma_row(c0, c1, c2, c3, wr + 3 * kWStride, a3);
    fma_row(c0, c1, c2, c3, wr + 4 * kWStride, a4);
    fma_row(c0, c1, c2, c3, wr + 5 * kWStride, a5);
    fma_row(c0, c1, c2, c3, wr + 6 * kWStride, a6);
    fma_row(c0, c1, c2, c3, wr + 7 * kWStride, a7);

    c0 = p0; c1 = p1; c2 = p2; c3 = p3;
  }

  if (lane < kNT) {
    float* ob = out + (((size_t)b * kO + g * kN) * kFP + fi) * (size_t)kNT + lane;
    const size_t s = (size_t)kFP * kNT;
    ob[0 * s] = a0;
    ob[1 * s] = a1;
    ob[2 * s] = a2;
    ob[3 * s] = a3;
    ob[4 * s] = a4;
    ob[5 * s] = a5;
    ob[6 * s] = a6;
    ob[7 * s] = a7;
  }
}

extern "C" void kernel_launch(void* const* d_in, const int* in_sizes, int n_in,
                              void* d_out, int out_size, void* d_ws, size_t ws_size,
                              hipStream_t stream) {
  const float* x  = (const float*)d_in[0];
  const float* wt = (const float*)d_in[1];
  float* out      = (float*)d_out;

  dim3 grid(kFP, kG, kB / 4);   // 64 x 8 x 4 = 2048 blocks of 256 threads
  lc2d_kernel<<<grid, 256, 0, stream>>>(x, wt, out);
}